// Round 4
// baseline (128.142 us; speedup 1.0000x reference)
//
#include <hip/hip_runtime.h>
#include <math.h>

#define BATCH 256
#define M 48
#define T 80
#define NF 6
#define EMIT 10
#define MM (M*M)        // 2304
#define KPL (MM/64)     // 36 keys per lane
#define NBIN 256
#define CAP 192
#define LOG2PI 1.8378770664093453f

typedef unsigned int u32;
typedef unsigned long long u64;

// Single-wave block: no __syncthreads anywhere. Wave-lockstep + in-order LDS
// provides all intra-block ordering. Grid = 256 = #CUs, so per-block critical
// path is the whole ballgame.
__global__ __launch_bounds__(64, 1)
void em_kernel(const float* __restrict__ g_logits,
               const float* __restrict__ g_traj,
               const float* __restrict__ g_cov,
               float* __restrict__ g_out)
{
    const int b = blockIdx.x;
    const int lane = threadIdx.x;
    const int SEL[3] = {29, 49, 79};

    // ---- LDS ~110 KB ----
    __shared__ __align__(16) float s_txy[M*T*2];   // staged traj (DMA), [m][t]{x,y}
    __shared__ __align__(16) float s_cv4[M*T*4];   // staged cov raw  (DMA), [m][t]{c00,c01,c10,c11}
    __shared__ float s_adj[MM];
    __shared__ float s_logits[M];
    __shared__ float s_probas[M];
    __shared__ float s_tsel[M*6];                  // [m][tt][d]
    __shared__ float s_d1[M*3];
    __shared__ __align__(16) float s_csel[M*3*4];  // [m][tt]{c00,c01,c11,pad}
    __shared__ __align__(16) float s_Pm[M*8];      // [m][n] padded to 8
    __shared__ float s_t6sel[NF*6];
    __shared__ float s_probas6[NF];
    __shared__ float s_prec[NF*3*3];
    __shared__ float s_ld[NF*3];
    __shared__ int   s_idx[NF];
    __shared__ u32   s_hist[NBIN];
    __shared__ u32   s_cand[CAP];
    __shared__ u32   s_cnt;
    __shared__ float s_v[2];

    const float* traj_b = g_traj + (size_t)b*(M*T*2);
    const float* cov_b  = g_cov  + (size_t)b*(M*T*4);

    // ========== small direct loads (issue + drain before DMA issue) ==========
    float myLogit = -1e30f;
    if (lane < M) myLogit = g_logits[b*M + lane];
    float selx[3], sely[3], cc0[3], cc1[3], cc2[3];
    #pragma unroll
    for (int r = 0; r < 3; ++r) {
        int i = lane + r*64;
        if (i < M*3) {
            int m = i/3, tt = i - (i/3)*3;
            float2 xy = ((const float2*)traj_b)[m*T + SEL[tt]];
            float4 cv = ((const float4*)cov_b)[m*T + SEL[tt]];
            selx[r]=xy.x; sely[r]=xy.y; cc0[r]=cv.x; cc1[r]=cv.y; cc2[r]=cv.w;
        }
    }
    if (lane < M) s_logits[lane] = myLogit;
    #pragma unroll
    for (int r = 0; r < 3; ++r) {
        int i = lane + r*64;
        if (i < M*3) {
            int m = i/3, tt = i - (i/3)*3;
            s_tsel[m*6+tt*2+0] = selx[r];
            s_tsel[m*6+tt*2+1] = sely[r];
            s_d1[i] = selx[r]*selx[r] + sely[r]*sely[r];
            s_csel[i*4+0]=cc0[r]; s_csel[i*4+1]=cc1[r]; s_csel[i*4+2]=cc2[r]; s_csel[i*4+3]=0.f;
        }
    }

    // ========== async DMA chunk 1: traj (30 x 1KB) ==========
    __builtin_amdgcn_sched_barrier(0);
    {
        const char* gt = (const char*)traj_b + lane*16;
        #pragma unroll
        for (int k = 0; k < 30; ++k)
            __builtin_amdgcn_global_load_lds(
                (const __attribute__((address_space(1))) u32*)(gt + k*1024),
                (__attribute__((address_space(3))) u32*)((char*)s_txy + k*1024), 16, 0, 0);
    }
    __builtin_amdgcn_sched_barrier(0);

    // ========== softmax over 48 logits (in-wave) ==========
    float mx = myLogit;
    #pragma unroll
    for (int off = 32; off; off >>= 1) mx = fmaxf(mx, __shfl_xor(mx, off));
    float pe = (lane < M) ? expf(myLogit - mx) : 0.f;
    float psum = pe;
    #pragma unroll
    for (int off = 32; off; off >>= 1) psum += __shfl_xor(psum, off);
    const float proba = pe / psum;
    if (lane < M) s_probas[lane] = proba;

    // ========== distance keys (tt=2), kept in registers ==========
    float key[KPL];
    #pragma unroll
    for (int c = 0; c < KPL; ++c) {
        int e = lane + c*64;
        int m = e/M, n = e - (e/M)*M;
        float dot = s_tsel[m*6+4]*s_tsel[n*6+4] + s_tsel[m*6+5]*s_tsel[n*6+5];
        float v = s_d1[m*3+2] + s_d1[n*3+2] - 2.0f*dot;
        key[c] = sqrtf(fmaxf(v, 0.0f));
    }
    float kmax = 0.f;
    #pragma unroll
    for (int c = 0; c < KPL; ++c) kmax = fmaxf(kmax, key[c]);
    #pragma unroll
    for (int off = 32; off; off >>= 1) kmax = fmaxf(kmax, __shfl_xor(kmax, off));
    const float scale = 256.0f / kmax;

    // linear-bin histogram (value-monotone => exact rank recovery)
    s_hist[lane]=0; s_hist[lane+64]=0; s_hist[lane+128]=0; s_hist[lane+192]=0;
    #pragma unroll
    for (int c = 0; c < KPL; ++c) {
        int bin = (int)(key[c]*scale); bin = bin > 255 ? 255 : bin;
        atomicAdd(&s_hist[bin], 1u);
    }
    uint4 hv = ((const uint4*)s_hist)[lane];
    u32 s4 = hv.x + hv.y + hv.z + hv.w;
    u32 cum = s4;
    #pragma unroll
    for (int off = 1; off < 64; off <<= 1) {
        u32 u = __shfl_up(cum, off);
        if (lane >= off) cum += u;
    }

    // exact order stats 345 & 346
    #pragma unroll 1
    for (int ri = 0; ri < 2; ++ri) {
        const u32 target = 345u + (u32)ri;
        u64 bmask = __ballot(cum > target);
        int g = __builtin_ctzll(bmask);
        int binIdx = 0; u32 binStart = 0;
        if (lane == g) {
            u32 exc = cum - s4;
            int bi2 = lane*4;
            if (exc + hv.x > target)      { binIdx = bi2;   binStart = exc; }
            else { exc += hv.x;
                if (exc + hv.y > target)  { binIdx = bi2+1; binStart = exc; }
                else { exc += hv.y;
                    if (exc + hv.z > target) { binIdx = bi2+2; binStart = exc; }
                    else { exc += hv.z;       binIdx = bi2+3; binStart = exc; } } }
        }
        binIdx   = __shfl(binIdx, g);
        binStart = (u32)__shfl((int)binStart, g);
        if (lane == 0) s_cnt = 0;
        #pragma unroll
        for (int c = 0; c < KPL; ++c) {
            int bin = (int)(key[c]*scale); bin = bin > 255 ? 255 : bin;
            if (bin == binIdx) {
                u32 p = atomicAdd(&s_cnt, 1u);
                if (p < CAP) s_cand[p] = __float_as_uint(key[c]);
            }
        }
        u32 cnt = s_cnt; if (cnt > CAP) cnt = CAP;
        u32 own0=0xFFFFFFFFu, own1=0xFFFFFFFFu, own2=0xFFFFFFFFu;
        if ((u32)lane      < cnt) own0 = s_cand[lane];
        if ((u32)lane+64u  < cnt) own1 = s_cand[lane+64];
        if ((u32)lane+128u < cnt) own2 = s_cand[lane+128];
        u32 cl0=0,ce0=0, cl1=0,ce1=0, cl2=0,ce2=0;
        for (u32 i = 0; i < cnt; ++i) {
            u32 v = s_cand[i];     // broadcast read
            cl0 += (v < own0); ce0 += (v == own0);
            cl1 += (v < own1); ce1 += (v == own1);
            cl2 += (v < own2); ce2 += (v == own2);
        }
        if ((u32)lane      < cnt && binStart+cl0 <= target && target < binStart+cl0+ce0) s_v[ri] = __uint_as_float(own0);
        if ((u32)lane+64u  < cnt && binStart+cl1 <= target && target < binStart+cl1+ce1) s_v[ri] = __uint_as_float(own1);
        if ((u32)lane+128u < cnt && binStart+cl2 <= target && target < binStart+cl2+ce2) s_v[ri] = __uint_as_float(own2);
    }
    const float qi = 0.15f * 2303.0f;
    const float fr = qi - floorf(qi);
    const float thr = s_v[0]*(1.0f - fr) + s_v[1]*fr;

    // ========== async DMA chunk 2: cov first half (30 x 1KB) ==========
    __builtin_amdgcn_sched_barrier(0);
    {
        const char* gc = (const char*)cov_b + lane*16;
        #pragma unroll
        for (int k = 0; k < 30; ++k)
            __builtin_amdgcn_global_load_lds(
                (const __attribute__((address_space(1))) u32*)(gc + k*1024),
                (__attribute__((address_space(3))) u32*)((char*)s_cv4 + k*1024), 16, 0, 0);
    }
    __builtin_amdgcn_sched_barrier(0);

    // ========== adjacency (recompute tt=0,1; reuse key for tt=2) ==========
    #pragma unroll
    for (int c = 0; c < KPL; ++c) {
        int e = lane + c*64;
        int m = e/M, n = e - (e/M)*M;
        float d0 = s_tsel[m*6+0]*s_tsel[n*6+0] + s_tsel[m*6+1]*s_tsel[n*6+1];
        float r0 = sqrtf(fmaxf(s_d1[m*3+0] + s_d1[n*3+0] - 2.0f*d0, 0.0f));
        float d1v = s_tsel[m*6+2]*s_tsel[n*6+2] + s_tsel[m*6+3]*s_tsel[n*6+3];
        float r1 = sqrtf(fmaxf(s_d1[m*3+1] + s_d1[n*3+1] - 2.0f*d1v, 0.0f));
        bool a = (key[c] <= thr) && (r0 <= thr) && (r1 <= thr);
        s_adj[e] = a ? 1.0f : 0.0f;
    }

    // ========== async DMA chunk 3: cov second half ==========
    __builtin_amdgcn_sched_barrier(0);
    {
        const char* gc = (const char*)cov_b + lane*16;
        #pragma unroll
        for (int k = 30; k < 60; ++k)
            __builtin_amdgcn_global_load_lds(
                (const __attribute__((address_space(1))) u32*)(gc + k*1024),
                (__attribute__((address_space(3))) u32*)((char*)s_cv4 + k*1024), 16, 0, 0);
    }
    __builtin_amdgcn_sched_barrier(0);

    // ========== greedy selection of 6 modes (in-wave) ==========
    const int m = (lane < M) ? lane : (M-1);
    {
        float base = 0.f;
        #pragma unroll
        for (int n = 0; n < M; ++n) base += s_adj[n*M+m] * s_probas[n];
        float worked = 1.f;
        #pragma unroll 1
        for (int k = 0; k < NF; ++k) {
            float sc = (lane < M) ? base*worked : -1.f;
            int bi = lane;
            #pragma unroll
            for (int off = 32; off; off >>= 1) {
                float so = __shfl_down(sc, off);
                int io = __shfl_down(bi, off);
                if (so > sc || (so == sc && io < bi)) { sc = so; bi = io; }
            }
            int amax = __shfl(bi, 0);   // first-max == jnp.argmax
            if (lane == 0) s_idx[k] = amax;
            worked *= (1.f - s_adj[amax*M+m]);
        }
    }

    // ========== EM init ==========
    if (lane < NF) {
        float mx6 = -1e30f;
        for (int j = 0; j < NF; ++j) mx6 = fmaxf(mx6, s_logits[s_idx[j]]);
        float sum6 = 0.f;
        for (int j = 0; j < NF; ++j) sum6 += expf(s_logits[s_idx[j]] - mx6);
        s_probas6[lane] = expf(s_logits[s_idx[lane]] - mx6) / sum6;
    }
    if (lane < NF*3) {
        int n = lane/3, tt = lane - (lane/3)*3;
        int m0 = s_idx[n];
        s_t6sel[n*6+tt*2+0] = s_tsel[m0*6+tt*2+0];
        s_t6sel[n*6+tt*2+1] = s_tsel[m0*6+tt*2+1];
        float c00 = s_csel[(m0*3+tt)*4+0];
        float c01 = s_csel[(m0*3+tt)*4+1];
        float c11 = s_csel[(m0*3+tt)*4+2];
        float det = c00*c11 - c01*c01;
        s_prec[lane*3+0] =  c11/det;
        s_prec[lane*3+1] = -c01/det;
        s_prec[lane*3+2] =  c00/det;
        s_ld[lane] = logf(det);
    }

    // ========== EM iterations (single wave, no barriers) ==========
    float tm0=s_tsel[m*6+0], tm1=s_tsel[m*6+1], tm2=s_tsel[m*6+2],
          tm3=s_tsel[m*6+3], tm4=s_tsel[m*6+4], tm5=s_tsel[m*6+5];
    const int item  = lane/3;              // M-step mapping (lanes < 54)
    const int chunk = lane - item*3;
    const int mn    = item/3;
    const int mtt   = item - (item/3)*3;

    #pragma unroll 1
    for (int it = 0; it < EMIT; ++it) {
        // ---- E-step: lane = m ----
        float num[NF]; float den = 1e-8f;
        #pragma unroll
        for (int n = 0; n < NF; ++n) {
            float lsum = s_ld[n*3+0] + s_ld[n*3+1] + s_ld[n*3+2];
            float dx0 = s_t6sel[n*6+0]-tm0, dy0 = s_t6sel[n*6+1]-tm1;
            float dx1 = s_t6sel[n*6+2]-tm2, dy1 = s_t6sel[n*6+3]-tm3;
            float dx2 = s_t6sel[n*6+4]-tm4, dy2 = s_t6sel[n*6+5]-tm5;
            float q = s_prec[(n*3+0)*3+0]*dx0*dx0 + 2.f*s_prec[(n*3+0)*3+1]*dx0*dy0 + s_prec[(n*3+0)*3+2]*dy0*dy0
                    + s_prec[(n*3+1)*3+0]*dx1*dx1 + 2.f*s_prec[(n*3+1)*3+1]*dx1*dy1 + s_prec[(n*3+1)*3+2]*dy1*dy1
                    + s_prec[(n*3+2)*3+0]*dx2*dx2 + 2.f*s_prec[(n*3+2)*3+1]*dx2*dy2 + s_prec[(n*3+2)*3+2]*dy2*dy2;
            num[n] = (expf(-3.f*LOG2PI - 0.5f*lsum - 0.5f*q) + 1e-8f) * s_probas6[n];
            den += num[n];
        }
        float f = proba / den;
        if (lane < M) {
            *(float4*)&s_Pm[m*8]   = make_float4(num[0]*f, num[1]*f, num[2]*f, num[3]*f);
            *(float2*)&s_Pm[m*8+4] = make_float2(num[4]*f, num[5]*f);
        }
        if (it == EMIT-1) break;

        // ---- selector-only M-step: 54 lanes = 18 items x 3 m-chunks ----
        if (lane < 54) {
            float SP=0,S1x=0,S1y=0,Sxx=0,Sxy=0,Syy=0,Cs0=0,Cs1=0,Cs2=0;
            int mbase = chunk*16;
            #pragma unroll 4
            for (int k = 0; k < 16; ++k) {
                int mm = mbase + k;
                float p = s_Pm[mm*8+mn];
                float x = s_tsel[mm*6+mtt*2+0];
                float y = s_tsel[mm*6+mtt*2+1];
                float4 c4 = *(const float4*)&s_csel[(mm*3+mtt)*4];
                SP += p; S1x += p*x; S1y += p*y;
                Sxx += p*x*x; Sxy += p*x*y; Syy += p*y*y;
                Cs0 += p*c4.x; Cs1 += p*c4.y; Cs2 += p*c4.z;
            }
            #define CMB(v) { float a1_=__shfl_down(v,1), a2_=__shfl_down(v,2); v += a1_ + a2_; }
            CMB(SP) CMB(S1x) CMB(S1y) CMB(Sxx) CMB(Sxy) CMB(Syy) CMB(Cs0) CMB(Cs1) CMB(Cs2)
            if (chunk == 0) {
                float p6 = SP;
                if (mtt == 0) s_probas6[mn] = SP;
                float tx = S1x/p6, ty = S1y/p6;
                float c00 = (Cs0 + (Sxx - S1x*tx)) / p6;
                float c01 = (Cs1 + (Sxy - S1x*ty)) / p6;
                float c11 = (Cs2 + (Syy - S1y*ty)) / p6;
                float det = c00*c11 - c01*c01;
                s_prec[item*3+0] =  c11/det;
                s_prec[item*3+1] = -c01/det;
                s_prec[item*3+2] =  c00/det;
                s_ld[item] = logf(det);
                s_t6sel[mn*6+mtt*2+0] = tx;
                s_t6sel[mn*6+mtt*2+1] = ty;
            }
        }
    }

    // ========== final full-T M-step -> global (drain DMA first) ==========
    __builtin_amdgcn_s_waitcnt(0x0F70);   // vmcnt(0), ignore exp/lgkm
    float*  out_p = g_out;
    float2* out_t = (float2*)(g_out + BATCH*NF);
    float4* out_c = (float4*)(g_out + BATCH*NF + BATCH*NF*T*2);
    #pragma unroll 1
    for (int t = lane; t < T; t += 64) {
        float SP[NF]={0,0,0,0,0,0}, S1x[NF]={0,0,0,0,0,0}, S1y[NF]={0,0,0,0,0,0};
        float Sxx[NF]={0,0,0,0,0,0}, Sxy[NF]={0,0,0,0,0,0}, Syy[NF]={0,0,0,0,0,0};
        float C00[NF]={0,0,0,0,0,0}, C01[NF]={0,0,0,0,0,0}, C11[NF]={0,0,0,0,0,0};
        #pragma unroll 2
        for (int mm = 0; mm < M; ++mm) {
            float2 xy = ((const float2*)s_txy)[mm*T + t];
            float4 c4 = ((const float4*)s_cv4)[mm*T + t];
            float4 Pa = *(const float4*)&s_Pm[mm*8];
            float2 Pb = *(const float2*)&s_Pm[mm*8+4];
            float xx = xy.x*xy.x, xyv = xy.x*xy.y, yy = xy.y*xy.y;
            #define UPD(p, n) { SP[n]+=(p); S1x[n]+=(p)*xy.x; S1y[n]+=(p)*xy.y; \
                Sxx[n]+=(p)*xx; Sxy[n]+=(p)*xyv; Syy[n]+=(p)*yy; \
                C00[n]+=(p)*c4.x; C01[n]+=(p)*c4.y; C11[n]+=(p)*c4.w; }
            UPD(Pa.x,0) UPD(Pa.y,1) UPD(Pa.z,2) UPD(Pa.w,3) UPD(Pb.x,4) UPD(Pb.y,5)
            #undef UPD
        }
        #pragma unroll
        for (int n = 0; n < NF; ++n) {
            float p6 = SP[n];
            float tx = S1x[n]/p6, ty = S1y[n]/p6;
            float c00 = (C00[n] + (Sxx[n] - S1x[n]*tx)) / p6;
            float c01 = (C01[n] + (Sxy[n] - S1x[n]*ty)) / p6;
            float c11 = (C11[n] + (Syy[n] - S1y[n]*ty)) / p6;
            size_t o = (size_t)(b*NF + n)*T + t;
            out_t[o] = make_float2(tx, ty);
            out_c[o] = make_float4(c00, c01, c01, c11);
        }
    }
    if (lane < NF) {
        float sp = 0.f;
        for (int mm = 0; mm < M; ++mm) sp += s_Pm[mm*8+lane];
        out_p[b*NF + lane] = sp;
    }
}

extern "C" void kernel_launch(void* const* d_in, const int* in_sizes, int n_in,
                              void* d_out, int out_size, void* d_ws, size_t ws_size,
                              hipStream_t stream) {
    const float* logits = (const float*)d_in[0];
    const float* traj   = (const float*)d_in[1];
    const float* cov    = (const float*)d_in[2];
    float* out = (float*)d_out;
    em_kernel<<<dim3(BATCH), dim3(64), 0, stream>>>(logits, traj, cov, out);
}

// Round 5
// 122.345 us; speedup vs baseline: 1.0474x; 1.0474x over previous
//
#include <hip/hip_runtime.h>
#include <math.h>

#define BATCH 256
#define M 48
#define T 80
#define NF 6
#define EMIT 10
#define MM (M*M)        // 2304
#define KPL (MM/64)     // 36 keys per lane
#define LOG2PI 1.8378770664093453f

typedef unsigned int u32;
typedef unsigned long long u64;

// 4 waves/block, ONE __syncthreads total. All serial phases computed
// REDUNDANTLY by each wave (identical results; private state per wave;
// shared arrays receive identical-value writes). Only DMA staging and the
// final full-T M-step are split across waves.
__global__ __launch_bounds__(256, 1)
void em_kernel(const float* __restrict__ g_logits,
               const float* __restrict__ g_traj,
               const float* __restrict__ g_cov,
               float* __restrict__ g_out)
{
    const int b = blockIdx.x;
    const int tid = threadIdx.x;
    const int lane = tid & 63;
    const int wv = tid >> 6;
    const int SEL[3] = {29, 49, 79};

    // ---- LDS ~115 KB ----
    __shared__ __align__(16) float s_txy[M*T*2];   // staged traj (DMA)
    __shared__ __align__(16) float s_cv4[M*T*4];   // staged cov (DMA)
    __shared__ float s_adj[MM];                    // shared, identical writes
    __shared__ float s_logits[M];
    __shared__ float s_probas[M];
    __shared__ float s_tsel[M*6];                  // [m][tt][d]
    __shared__ float s_d1[M*3];
    __shared__ __align__(16) float s_csel[M*3*4];  // [m][tt]{c00,c01,c11,pad}
    // per-wave private:
    __shared__ __align__(16) float s_Pm[4][M*8];   // [m][slot]: 0-2=n0..2,4-6=n3..5
    __shared__ float s_t6sel[4][NF*6];
    __shared__ float s_probas6[4][NF];
    __shared__ float s_prec[4][NF*3*3];
    __shared__ float s_ld[4][NF*3];
    __shared__ int   s_idx[4][8];
    __shared__ __align__(16) u32 s_hist[4][256];

    const float* traj_b = g_traj + (size_t)b*(M*T*2);
    const float* cov_b  = g_cov  + (size_t)b*(M*T*4);

    // ========== direct gathers (redundant per wave) ==========
    float myLogit = -1e30f;
    if (lane < M) myLogit = g_logits[b*M + lane];
    float selx[3], sely[3], cc0[3], cc1[3], cc2[3];
    #pragma unroll
    for (int r = 0; r < 3; ++r) {
        int i = lane + r*64;
        if (i < M*3) {
            int m = i/3, tt = i - (i/3)*3;
            float2 xy = ((const float2*)traj_b)[m*T + SEL[tt]];
            float4 cv = ((const float4*)cov_b)[m*T + SEL[tt]];
            selx[r]=xy.x; sely[r]=xy.y; cc0[r]=cv.x; cc1[r]=cv.y; cc2[r]=cv.w;
        }
    }

    // ========== DMA staging, split 4 ways (per-wave vmcnt) ==========
    __builtin_amdgcn_sched_barrier(0);
    {
        const char* gt = (const char*)traj_b + lane*16;
        char* lt = (char*)s_txy;
        #pragma unroll 2
        for (int k = wv; k < 30; k += 4)
            __builtin_amdgcn_global_load_lds(
                (const __attribute__((address_space(1))) u32*)(gt + k*1024),
                (__attribute__((address_space(3))) u32*)(lt + k*1024), 16, 0, 0);
        const char* gc = (const char*)cov_b + lane*16;
        char* lc = (char*)s_cv4;
        #pragma unroll 2
        for (int k = wv; k < 60; k += 4)
            __builtin_amdgcn_global_load_lds(
                (const __attribute__((address_space(1))) u32*)(gc + k*1024),
                (__attribute__((address_space(3))) u32*)(lc + k*1024), 16, 0, 0);
    }
    __builtin_amdgcn_sched_barrier(0);

    // ========== stage selector data (redundant identical writes) ==========
    if (lane < M) s_logits[lane] = myLogit;
    #pragma unroll
    for (int r = 0; r < 3; ++r) {
        int i = lane + r*64;
        if (i < M*3) {
            int m = i/3, tt = i - (i/3)*3;
            s_tsel[m*6+tt*2+0] = selx[r];
            s_tsel[m*6+tt*2+1] = sely[r];
            s_d1[i] = selx[r]*selx[r] + sely[r]*sely[r];
            s_csel[i*4+0]=cc0[r]; s_csel[i*4+1]=cc1[r]; s_csel[i*4+2]=cc2[r]; s_csel[i*4+3]=0.f;
        }
    }

    // ========== softmax (in-wave, registers) ==========
    float mx = myLogit;
    #pragma unroll
    for (int off = 32; off; off >>= 1) mx = fmaxf(mx, __shfl_xor(mx, off));
    float pe = (lane < M) ? __expf(myLogit - mx) : 0.f;
    float psum = pe;
    #pragma unroll
    for (int off = 32; off; off >>= 1) psum += __shfl_xor(psum, off);
    const float proba = pe / psum;
    if (lane < M) s_probas[lane] = proba;

    // ========== distance keys (tt=2) in registers ==========
    u32 key[KPL];
    #pragma unroll
    for (int c = 0; c < KPL; ++c) {
        int e = lane + c*64;
        int m = e/M, n = e - (e/M)*M;
        float dot = s_tsel[m*6+4]*s_tsel[n*6+4] + s_tsel[m*6+5]*s_tsel[n*6+5];
        float v = s_d1[m*3+2] + s_d1[n*3+2] - 2.0f*dot;
        key[c] = __float_as_uint(sqrtf(fmaxf(v, 0.0f)));   // nonneg: IEEE order == int order
    }

    // ========== exact order stat 345 via per-wave radix select ==========
    u32* hist = &s_hist[wv][0];
    int target = 345;
    u32 prefix = 0u, pmask = 0u;
    #pragma unroll 1
    for (int shift = 24; shift >= 0; shift -= 8) {
        ((uint4*)hist)[lane] = make_uint4(0,0,0,0);
        #pragma unroll
        for (int c = 0; c < KPL; ++c) {
            if ((key[c] & pmask) == prefix)
                atomicAdd(&hist[(key[c] >> shift) & 255u], 1u);
        }
        uint4 hv = ((const uint4*)hist)[lane];
        u32 s4 = hv.x + hv.y + hv.z + hv.w;
        u32 cum = s4;
        #pragma unroll
        for (int off = 1; off < 64; off <<= 1) {
            u32 u = __shfl_up(cum, off);
            if (lane >= off) cum += u;
        }
        u64 bmask = __ballot(cum > (u32)target);
        int g = __builtin_ctzll(bmask);
        int dig = 0; u32 binstart = 0;
        if (lane == g) {
            u32 exc = cum - s4;
            int bi2 = lane*4;
            if (exc + hv.x > (u32)target)      { dig = bi2;   binstart = exc; }
            else { exc += hv.x;
                if (exc + hv.y > (u32)target)  { dig = bi2+1; binstart = exc; }
                else { exc += hv.y;
                    if (exc + hv.z > (u32)target) { dig = bi2+2; binstart = exc; }
                    else { exc += hv.z;            dig = bi2+3; binstart = exc; } } }
        }
        dig = __shfl(dig, g);
        binstart = (u32)__shfl((int)binstart, g);
        target -= (int)binstart;
        prefix |= ((u32)dig) << shift;
        pmask  |= (255u << shift);
    }
    const u32 k1 = prefix;
    const float v1f = __uint_as_float(k1);

    // order stat 346: count(<=v345) >= 347 -> v345, else min{x > v345}
    float v2f;
    {
        u32 cnt = 0, mng = 0xFFFFFFFFu;
        #pragma unroll
        for (int c = 0; c < KPL; ++c) {
            if (key[c] <= k1) cnt++;
            else mng = (key[c] < mng) ? key[c] : mng;
        }
        #pragma unroll
        for (int off = 32; off > 0; off >>= 1) {
            cnt += __shfl_down(cnt, off);
            u32 mo = (u32)__shfl_down((int)mng, off);
            mng = (mo < mng) ? mo : mng;
        }
        u32 ct = (u32)__shfl((int)cnt, 0);
        u32 mt = (u32)__shfl((int)mng, 0);
        v2f = (ct >= 347u) ? v1f : __uint_as_float(mt);
    }
    const float qi = 0.15f * 2303.0f;
    const float fr = qi - floorf(qi);
    const float thr = v1f*(1.0f - fr) + v2f*fr;

    // ========== adjacency (redundant identical writes) ==========
    #pragma unroll
    for (int c = 0; c < KPL; ++c) {
        int e = lane + c*64;
        int m = e/M, n = e - (e/M)*M;
        float d0 = s_tsel[m*6+0]*s_tsel[n*6+0] + s_tsel[m*6+1]*s_tsel[n*6+1];
        float r0 = sqrtf(fmaxf(s_d1[m*3+0] + s_d1[n*3+0] - 2.0f*d0, 0.0f));
        float d1v = s_tsel[m*6+2]*s_tsel[n*6+2] + s_tsel[m*6+3]*s_tsel[n*6+3];
        float r1 = sqrtf(fmaxf(s_d1[m*3+1] + s_d1[n*3+1] - 2.0f*d1v, 0.0f));
        bool a = (__uint_as_float(key[c]) <= thr) && (r0 <= thr) && (r1 <= thr);
        s_adj[e] = a ? 1.0f : 0.0f;
    }

    // ========== greedy selection (redundant per wave) ==========
    const int m = (lane < M) ? lane : (M-1);
    {
        float base = 0.f;
        #pragma unroll
        for (int n = 0; n < M; ++n) base += s_adj[n*M+m] * s_probas[n];
        float worked = 1.f;
        #pragma unroll 1
        for (int k = 0; k < NF; ++k) {
            float sc = (lane < M) ? base*worked : -1.f;
            int bi = lane;
            #pragma unroll
            for (int off = 32; off; off >>= 1) {
                float so = __shfl_down(sc, off);
                int io = __shfl_down(bi, off);
                if (so > sc || (so == sc && io < bi)) { sc = so; bi = io; }
            }
            int amax = __shfl(bi, 0);   // first-max == jnp.argmax
            if (lane == 0) s_idx[wv][k] = amax;
            worked *= (1.f - s_adj[amax*M+m]);
        }
    }

    // ========== EM init (private per wave) ==========
    if (lane < NF) {
        float mx6 = -1e30f;
        #pragma unroll
        for (int j = 0; j < NF; ++j) mx6 = fmaxf(mx6, s_logits[s_idx[wv][j]]);
        float sum6 = 0.f;
        #pragma unroll
        for (int j = 0; j < NF; ++j) sum6 += __expf(s_logits[s_idx[wv][j]] - mx6);
        s_probas6[wv][lane] = __expf(s_logits[s_idx[wv][lane]] - mx6) / sum6;
    }
    if (lane < NF*3) {
        int n = lane/3, tt = lane - (lane/3)*3;
        int m0 = s_idx[wv][n];
        s_t6sel[wv][n*6+tt*2+0] = s_tsel[m0*6+tt*2+0];
        s_t6sel[wv][n*6+tt*2+1] = s_tsel[m0*6+tt*2+1];
        float c00 = s_csel[(m0*3+tt)*4+0];
        float c01 = s_csel[(m0*3+tt)*4+1];
        float c11 = s_csel[(m0*3+tt)*4+2];
        float det = c00*c11 - c01*c01;
        s_prec[wv][lane*3+0] =  c11/det;
        s_prec[wv][lane*3+1] = -c01/det;
        s_prec[wv][lane*3+2] =  c00/det;
        s_ld[wv][lane] = __logf(det);
    }

    // ========== EM loop (redundant per wave, zero barriers) ==========
    float tm0=s_tsel[m*6+0], tm1=s_tsel[m*6+1], tm2=s_tsel[m*6+2],
          tm3=s_tsel[m*6+3], tm4=s_tsel[m*6+4], tm5=s_tsel[m*6+5];
    const int item  = lane/3;                 // selector M-step mapping (lanes<54)
    const int chunk = lane - item*3;
    const int mn    = item/3;
    const int mtt   = item - (item/3)*3;
    const int mslot = (mn < 3) ? mn : mn + 1; // Pm slot for component mn

    #pragma unroll 1
    for (int it = 0; it < EMIT; ++it) {
        // ---- E-step: lane = m ----
        float num[NF]; float den = 1e-8f;
        #pragma unroll
        for (int n = 0; n < NF; ++n) {
            float lsum = s_ld[wv][n*3+0] + s_ld[wv][n*3+1] + s_ld[wv][n*3+2];
            float dx0 = s_t6sel[wv][n*6+0]-tm0, dy0 = s_t6sel[wv][n*6+1]-tm1;
            float dx1 = s_t6sel[wv][n*6+2]-tm2, dy1 = s_t6sel[wv][n*6+3]-tm3;
            float dx2 = s_t6sel[wv][n*6+4]-tm4, dy2 = s_t6sel[wv][n*6+5]-tm5;
            float q = s_prec[wv][(n*3+0)*3+0]*dx0*dx0 + 2.f*s_prec[wv][(n*3+0)*3+1]*dx0*dy0 + s_prec[wv][(n*3+0)*3+2]*dy0*dy0
                    + s_prec[wv][(n*3+1)*3+0]*dx1*dx1 + 2.f*s_prec[wv][(n*3+1)*3+1]*dx1*dy1 + s_prec[wv][(n*3+1)*3+2]*dy1*dy1
                    + s_prec[wv][(n*3+2)*3+0]*dx2*dx2 + 2.f*s_prec[wv][(n*3+2)*3+1]*dx2*dy2 + s_prec[wv][(n*3+2)*3+2]*dy2*dy2;
            num[n] = (__expf(-3.f*LOG2PI - 0.5f*lsum - 0.5f*q) + 1e-8f) * s_probas6[wv][n];
            den += num[n];
        }
        float f = proba / den;
        if (lane < M) {
            *(float4*)&s_Pm[wv][m*8]   = make_float4(num[0]*f, num[1]*f, num[2]*f, 0.f);
            *(float4*)&s_Pm[wv][m*8+4] = make_float4(num[3]*f, num[4]*f, num[5]*f, 0.f);
        }
        if (it == EMIT-1) break;

        // ---- selector-only M-step: 54 lanes = 18 items x 3 m-chunks ----
        if (lane < 54) {
            float SP=0,S1x=0,S1y=0,Sxx=0,Sxy=0,Syy=0,Cs0=0,Cs1=0,Cs2=0;
            int mbase = chunk*16;
            #pragma unroll 4
            for (int k = 0; k < 16; ++k) {
                int mm = mbase + k;
                float p = s_Pm[wv][mm*8 + mslot];
                float x = s_tsel[mm*6+mtt*2+0];
                float y = s_tsel[mm*6+mtt*2+1];
                float4 c4 = *(const float4*)&s_csel[(mm*3+mtt)*4];
                SP += p; S1x += p*x; S1y += p*y;
                Sxx += p*x*x; Sxy += p*x*y; Syy += p*y*y;
                Cs0 += p*c4.x; Cs1 += p*c4.y; Cs2 += p*c4.z;
            }
            #define CMB(v) { float a1_=__shfl_down(v,1), a2_=__shfl_down(v,2); v += a1_ + a2_; }
            CMB(SP) CMB(S1x) CMB(S1y) CMB(Sxx) CMB(Sxy) CMB(Syy) CMB(Cs0) CMB(Cs1) CMB(Cs2)
            if (chunk == 0) {
                float p6 = SP;
                if (mtt == 0) s_probas6[wv][mn] = SP;
                float tx = S1x/p6, ty = S1y/p6;
                float c00 = (Cs0 + (Sxx - S1x*tx)) / p6;
                float c01 = (Cs1 + (Sxy - S1x*ty)) / p6;
                float c11 = (Cs2 + (Syy - S1y*ty)) / p6;
                float det = c00*c11 - c01*c01;
                s_prec[wv][item*3+0] =  c11/det;
                s_prec[wv][item*3+1] = -c01/det;
                s_prec[wv][item*3+2] =  c00/det;
                s_ld[wv][item] = __logf(det);
                s_t6sel[wv][mn*6+mtt*2+0] = tx;
                s_t6sel[wv][mn*6+mtt*2+1] = ty;
            }
        }
    }

    // ========== THE one barrier: staging quarters must all be visible ==========
    __syncthreads();

    // ========== final full-T M-step, split 4 ways: 160 items=(t,half) ==========
    float*  out_p = g_out;
    float2* out_t = (float2*)(g_out + BATCH*NF);
    float4* out_c = (float4*)(g_out + BATCH*NF + BATCH*NF*T*2);
    if (lane < 40) {
        int it2 = wv*40 + lane;       // 0..159
        int t = it2 >> 1, half = it2 & 1;
        float SP[3]={0,0,0}, S1x[3]={0,0,0}, S1y[3]={0,0,0};
        float Sxx[3]={0,0,0}, Sxy[3]={0,0,0}, Syy[3]={0,0,0};
        float C00[3]={0,0,0}, C01[3]={0,0,0}, C11[3]={0,0,0};
        #pragma unroll 4
        for (int mm = 0; mm < M; ++mm) {
            float2 xy = ((const float2*)s_txy)[mm*T + t];
            float4 c4 = ((const float4*)s_cv4)[mm*T + t];
            float4 pq = *(const float4*)&s_Pm[wv][mm*8 + half*4];
            float p[3] = {pq.x, pq.y, pq.z};
            float xx = xy.x*xy.x, xyv = xy.x*xy.y, yy = xy.y*xy.y;
            #pragma unroll
            for (int j = 0; j < 3; ++j) {
                SP[j]+=p[j]; S1x[j]+=p[j]*xy.x; S1y[j]+=p[j]*xy.y;
                Sxx[j]+=p[j]*xx; Sxy[j]+=p[j]*xyv; Syy[j]+=p[j]*yy;
                C00[j]+=p[j]*c4.x; C01[j]+=p[j]*c4.y; C11[j]+=p[j]*c4.w;
            }
        }
        #pragma unroll
        for (int j = 0; j < 3; ++j) {
            int n = half*3 + j;
            float p6 = SP[j];
            float tx = S1x[j]/p6, ty = S1y[j]/p6;
            float c00 = (C00[j] + (Sxx[j] - S1x[j]*tx)) / p6;
            float c01 = (C01[j] + (Sxy[j] - S1x[j]*ty)) / p6;
            float c11 = (C11[j] + (Syy[j] - S1y[j]*ty)) / p6;
            size_t o = (size_t)(b*NF + n)*T + t;
            out_t[o] = make_float2(tx, ty);
            out_c[o] = make_float4(c00, c01, c01, c11);
        }
    }
    if (wv == 0 && lane < NF) {
        int slot = (lane < 3) ? lane : lane + 1;
        float sp = 0.f;
        for (int mm = 0; mm < M; ++mm) sp += s_Pm[0][mm*8 + slot];
        out_p[b*NF + lane] = sp;
    }
}

extern "C" void kernel_launch(void* const* d_in, const int* in_sizes, int n_in,
                              void* d_out, int out_size, void* d_ws, size_t ws_size,
                              hipStream_t stream) {
    const float* logits = (const float*)d_in[0];
    const float* traj   = (const float*)d_in[1];
    const float* cov    = (const float*)d_in[2];
    float* out = (float*)d_out;
    em_kernel<<<dim3(BATCH), dim3(256), 0, stream>>>(logits, traj, cov, out);
}

// Round 6
// 112.962 us; speedup vs baseline: 1.1344x; 1.0831x over previous
//
#include <hip/hip_runtime.h>
#include <math.h>

#define BATCH 256
#define M 48
#define T 80
#define NF 6
#define EMIT 10
#define MM (M*M)        // 2304
#define KPL (MM/64)     // 36 keys per lane
#define LOG2PI 1.8378770664093453f

typedef unsigned int u32;
typedef unsigned long long u64;

// Raw workgroup sync: drains LDS (lgkm) only -- async global_load_lds DMA
// (vmcnt) stays in flight. "memory" clobber stops compiler caching LDS in regs.
#define WGSYNC()     __asm__ __volatile__("s_waitcnt lgkmcnt(0)\ns_barrier" ::: "memory")
#define WGSYNC_ALL() __asm__ __volatile__("s_waitcnt vmcnt(0) lgkmcnt(0)\ns_barrier" ::: "memory")

// 4 waves/block. Serial phases run REDUNDANTLY on all waves (free: wall time
// == one-wave time; identical-value shared writes are race-safe). Multi-
// iteration phases (DMA, selector M-step, final M-step) are SPLIT across
// waves. EM state double-buffered by iteration parity -> 1 barrier/iter.
__global__ __launch_bounds__(256, 1)
void em_kernel(const float* __restrict__ g_logits,
               const float* __restrict__ g_traj,
               const float* __restrict__ g_cov,
               float* __restrict__ g_out)
{
    const int b = blockIdx.x;
    const int tid = threadIdx.x;
    const int lane = tid & 63;
    const int wv = tid >> 6;
    const int SEL[3] = {29, 49, 79};

    // ---- LDS ~112 KB ----
    __shared__ __align__(16) float s_txy[M*T*2];   // staged traj (DMA)
    __shared__ __align__(16) float s_cv4[M*T*4];   // staged cov (DMA)
    __shared__ float s_adj[MM];
    __shared__ float s_logits[M];
    __shared__ float s_probas[M];
    __shared__ float s_tsel[M*6];                  // [m][tt][d]
    __shared__ float s_d1[M*3];
    __shared__ __align__(16) float s_csel[M*3*4];  // [m][tt]{c00,c01,c11,pad}
    __shared__ __align__(16) float s_Pm[M*8];      // slots: 0-2=n0..2, 4-6=n3..5
    __shared__ float s_t6sel[2][NF*6];             // ping-pong EM state
    __shared__ float s_probas6[2][NF];
    __shared__ float s_prec[2][NF*3*3];
    __shared__ float s_ld[2][NF*3];
    __shared__ int   s_idx[8];
    __shared__ __align__(16) u32 s_hist[4][256];   // per-wave radix hist

    const float* traj_b = g_traj + (size_t)b*(M*T*2);
    const float* cov_b  = g_cov  + (size_t)b*(M*T*4);

    // ========== direct gathers (redundant per wave) ==========
    float myLogit = -1e30f;
    if (lane < M) myLogit = g_logits[b*M + lane];
    float selx[3], sely[3], cc0[3], cc1[3], cc2[3];
    #pragma unroll
    for (int r = 0; r < 3; ++r) {
        int i = lane + r*64;
        if (i < M*3) {
            int m = i/3, tt = i - (i/3)*3;
            float2 xy = ((const float2*)traj_b)[m*T + SEL[tt]];
            float4 cv = ((const float4*)cov_b)[m*T + SEL[tt]];
            selx[r]=xy.x; sely[r]=xy.y; cc0[r]=cv.x; cc1[r]=cv.y; cc2[r]=cv.w;
        }
    }

    // ========== DMA staging, split 4 ways (per-wave vmcnt) ==========
    __builtin_amdgcn_sched_barrier(0);
    {
        const char* gt = (const char*)traj_b + lane*16;
        char* lt = (char*)s_txy;
        #pragma unroll 2
        for (int k = wv; k < 30; k += 4)
            __builtin_amdgcn_global_load_lds(
                (const __attribute__((address_space(1))) u32*)(gt + k*1024),
                (__attribute__((address_space(3))) u32*)(lt + k*1024), 16, 0, 0);
        const char* gc = (const char*)cov_b + lane*16;
        char* lc = (char*)s_cv4;
        #pragma unroll 2
        for (int k = wv; k < 60; k += 4)
            __builtin_amdgcn_global_load_lds(
                (const __attribute__((address_space(1))) u32*)(gc + k*1024),
                (__attribute__((address_space(3))) u32*)(lc + k*1024), 16, 0, 0);
    }
    __builtin_amdgcn_sched_barrier(0);

    // ========== stage selector data (redundant identical writes) ==========
    if (lane < M) s_logits[lane] = myLogit;
    #pragma unroll
    for (int r = 0; r < 3; ++r) {
        int i = lane + r*64;
        if (i < M*3) {
            int m = i/3, tt = i - (i/3)*3;
            s_tsel[m*6+tt*2+0] = selx[r];
            s_tsel[m*6+tt*2+1] = sely[r];
            s_d1[i] = selx[r]*selx[r] + sely[r]*sely[r];
            s_csel[i*4+0]=cc0[r]; s_csel[i*4+1]=cc1[r]; s_csel[i*4+2]=cc2[r]; s_csel[i*4+3]=0.f;
        }
    }

    // ========== softmax (in-wave, registers) ==========
    float mx = myLogit;
    #pragma unroll
    for (int off = 32; off; off >>= 1) mx = fmaxf(mx, __shfl_xor(mx, off));
    float pe = (lane < M) ? __expf(myLogit - mx) : 0.f;
    float psum = pe;
    #pragma unroll
    for (int off = 32; off; off >>= 1) psum += __shfl_xor(psum, off);
    const float proba = pe / psum;
    if (lane < M) s_probas[lane] = proba;

    // ========== SQUARED distance keys (tt=2); sqrt deferred ==========
    // order stats commute with monotone sqrt; clamp matches prior semantics
    u32 key[KPL];
    #pragma unroll
    for (int c = 0; c < KPL; ++c) {
        int e = lane + c*64;
        int m = e/M, n = e - (e/M)*M;
        float dot = s_tsel[m*6+4]*s_tsel[n*6+4] + s_tsel[m*6+5]*s_tsel[n*6+5];
        float v = s_d1[m*3+2] + s_d1[n*3+2] - 2.0f*dot;
        key[c] = __float_as_uint(fmaxf(v, 0.0f));   // nonneg: uint order == float order
    }

    // ========== exact order stat 345 via per-wave radix select ==========
    u32* hist = &s_hist[wv][0];
    int target = 345;
    u32 prefix = 0u, pmask = 0u;
    #pragma unroll 1
    for (int shift = 24; shift >= 0; shift -= 8) {
        ((uint4*)hist)[lane] = make_uint4(0,0,0,0);
        #pragma unroll
        for (int c = 0; c < KPL; ++c) {
            if ((key[c] & pmask) == prefix)
                atomicAdd(&hist[(key[c] >> shift) & 255u], 1u);
        }
        uint4 hv = ((const uint4*)hist)[lane];
        u32 s4 = hv.x + hv.y + hv.z + hv.w;
        u32 cum = s4;
        #pragma unroll
        for (int off = 1; off < 64; off <<= 1) {
            u32 u = __shfl_up(cum, off);
            if (lane >= off) cum += u;
        }
        u64 bmask = __ballot(cum > (u32)target);
        int g = __builtin_ctzll(bmask);
        int dig = 0; u32 binstart = 0;
        if (lane == g) {
            u32 exc = cum - s4;
            int bi2 = lane*4;
            if (exc + hv.x > (u32)target)      { dig = bi2;   binstart = exc; }
            else { exc += hv.x;
                if (exc + hv.y > (u32)target)  { dig = bi2+1; binstart = exc; }
                else { exc += hv.y;
                    if (exc + hv.z > (u32)target) { dig = bi2+2; binstart = exc; }
                    else { exc += hv.z;            dig = bi2+3; binstart = exc; } } }
        }
        dig = __shfl(dig, g);
        binstart = (u32)__shfl((int)binstart, g);
        target -= (int)binstart;
        prefix |= ((u32)dig) << shift;
        pmask  |= (255u << shift);
    }
    const u32 k1 = prefix;                 // squared order stat 345
    const float v1f = sqrtf(__uint_as_float(k1));

    // order stat 346 (squared): count(<=k1) >= 347 -> k1, else min{x > k1}
    float v2f;
    {
        u32 cnt = 0, mng = 0xFFFFFFFFu;
        #pragma unroll
        for (int c = 0; c < KPL; ++c) {
            if (key[c] <= k1) cnt++;
            else mng = (key[c] < mng) ? key[c] : mng;
        }
        #pragma unroll
        for (int off = 32; off > 0; off >>= 1) {
            cnt += __shfl_down(cnt, off);
            u32 mo = (u32)__shfl_down((int)mng, off);
            mng = (mo < mng) ? mo : mng;
        }
        u32 ct = (u32)__shfl((int)cnt, 0);
        u32 mt = (u32)__shfl((int)mng, 0);
        v2f = (ct >= 347u) ? v1f : sqrtf(__uint_as_float(mt));
    }
    const float qi = 0.15f * 2303.0f;
    const float fr = qi - floorf(qi);
    const float thr = v1f*(1.0f - fr) + v2f*fr;

    // convert to exact squared threshold: dthr = max{u : fl(sqrt(u)) <= thr}
    float dthr;
    {
        u32 ub = __float_as_uint(thr*thr);
        while (sqrtf(__uint_as_float(ub)) > thr) --ub;        // <=2 iters
        while (sqrtf(__uint_as_float(ub+1u)) <= thr) ++ub;    // <=2 iters
        dthr = __uint_as_float(ub);
    }

    // ========== adjacency, squared-space (redundant identical writes) ==========
    #pragma unroll
    for (int c = 0; c < KPL; ++c) {
        int e = lane + c*64;
        int m = e/M, n = e - (e/M)*M;
        float d0 = s_tsel[m*6+0]*s_tsel[n*6+0] + s_tsel[m*6+1]*s_tsel[n*6+1];
        float v0 = fmaxf(s_d1[m*3+0] + s_d1[n*3+0] - 2.0f*d0, 0.0f);
        float d1v = s_tsel[m*6+2]*s_tsel[n*6+2] + s_tsel[m*6+3]*s_tsel[n*6+3];
        float v1 = fmaxf(s_d1[m*3+1] + s_d1[n*3+1] - 2.0f*d1v, 0.0f);
        bool a = (__uint_as_float(key[c]) <= dthr) && (v0 <= dthr) && (v1 <= dthr);
        s_adj[e] = a ? 1.0f : 0.0f;
    }

    // ========== greedy selection (redundant per wave) ==========
    const int m = (lane < M) ? lane : (M-1);
    {
        float base = 0.f;
        #pragma unroll
        for (int n = 0; n < M; ++n) base += s_adj[n*M+m] * s_probas[n];
        float worked = 1.f;
        #pragma unroll 1
        for (int k = 0; k < NF; ++k) {
            float sc = (lane < M) ? base*worked : -1.f;
            int bi = lane;
            #pragma unroll
            for (int off = 32; off; off >>= 1) {
                float so = __shfl_down(sc, off);
                int io = __shfl_down(bi, off);
                if (so > sc || (so == sc && io < bi)) { sc = so; bi = io; }
            }
            int amax = __shfl(bi, 0);   // first-max == jnp.argmax
            if (lane == 0) s_idx[k] = amax;
            worked *= (1.f - s_adj[amax*M+m]);
        }
    }

    // ========== EM init -> buffer 0 (redundant identical writes) ==========
    if (lane < NF) {
        float mx6 = -1e30f;
        #pragma unroll
        for (int j = 0; j < NF; ++j) mx6 = fmaxf(mx6, s_logits[s_idx[j]]);
        float sum6 = 0.f;
        #pragma unroll
        for (int j = 0; j < NF; ++j) sum6 += __expf(s_logits[s_idx[j]] - mx6);
        s_probas6[0][lane] = __expf(s_logits[s_idx[lane]] - mx6) / sum6;
    }
    if (lane < NF*3) {
        int n = lane/3, tt = lane - (lane/3)*3;
        int m0 = s_idx[n];
        s_t6sel[0][n*6+tt*2+0] = s_tsel[m0*6+tt*2+0];
        s_t6sel[0][n*6+tt*2+1] = s_tsel[m0*6+tt*2+1];
        float c00 = s_csel[(m0*3+tt)*4+0];
        float c01 = s_csel[(m0*3+tt)*4+1];
        float c11 = s_csel[(m0*3+tt)*4+2];
        float det = c00*c11 - c01*c01;
        float rdet = __fdividef(1.0f, det);
        s_prec[0][lane*3+0] =  c11*rdet;
        s_prec[0][lane*3+1] = -c01*rdet;
        s_prec[0][lane*3+2] =  c00*rdet;
        s_ld[0][lane] = __logf(det);
    }

    // ========== EM loop: redundant E-step + SPLIT selector M-step ==========
    float tm0=s_tsel[m*6+0], tm1=s_tsel[m*6+1], tm2=s_tsel[m*6+2],
          tm3=s_tsel[m*6+3], tm4=s_tsel[m*6+4], tm5=s_tsel[m*6+5];
    const int gid = tid >> 3;          // 8-lane group id, 0..31 (18 active)
    const int sub = tid & 7;
    const int gn  = gid/3, gtt = gid - (gid/3)*3;      // valid when gid<18
    const int gslot = (gn < 3) ? gn : gn + 1;

    #pragma unroll 1
    for (int it = 0; it < EMIT; ++it) {
        const int cur = it & 1, nxt = cur ^ 1;
        const float* prC = s_prec[cur];
        const float* ldC = s_ld[cur];
        const float* t6C = s_t6sel[cur];
        const float* p6C = s_probas6[cur];

        // ---- E-step (all waves, lane = m): broadcast LDS reads ----
        float num[NF]; float den = 1e-8f;
        #pragma unroll
        for (int n = 0; n < NF; ++n) {
            float lsum = ldC[n*3+0] + ldC[n*3+1] + ldC[n*3+2];
            float dx0 = t6C[n*6+0]-tm0, dy0 = t6C[n*6+1]-tm1;
            float dx1 = t6C[n*6+2]-tm2, dy1 = t6C[n*6+3]-tm3;
            float dx2 = t6C[n*6+4]-tm4, dy2 = t6C[n*6+5]-tm5;
            float q = prC[(n*3+0)*3+0]*dx0*dx0 + 2.f*prC[(n*3+0)*3+1]*dx0*dy0 + prC[(n*3+0)*3+2]*dy0*dy0
                    + prC[(n*3+1)*3+0]*dx1*dx1 + 2.f*prC[(n*3+1)*3+1]*dx1*dy1 + prC[(n*3+1)*3+2]*dy1*dy1
                    + prC[(n*3+2)*3+0]*dx2*dx2 + 2.f*prC[(n*3+2)*3+1]*dx2*dy2 + prC[(n*3+2)*3+2]*dy2*dy2;
            num[n] = (__expf(-3.f*LOG2PI - 0.5f*lsum - 0.5f*q) + 1e-8f) * p6C[n];
            den += num[n];
        }
        float f = __fdividef(proba, den);
        if (lane < M) {   // identical-value writes from all 4 waves: race-safe
            *(float4*)&s_Pm[m*8]   = make_float4(num[0]*f, num[1]*f, num[2]*f, 0.f);
            *(float4*)&s_Pm[m*8+4] = make_float4(num[3]*f, num[4]*f, num[5]*f, 0.f);
        }
        if (it == EMIT-1) break;

        // ---- selector M-step SPLIT: 18 items x 8-lane groups, 6-deep loops ----
        if (gid < 18) {
            float SP=0,S1x=0,S1y=0,Sxx=0,Sxy=0,Syy=0,C0=0,C1=0,C2=0;
            #pragma unroll
            for (int k = 0; k < 6; ++k) {
                int mm = sub*6 + k;
                float p = s_Pm[mm*8 + gslot];     // own-wave writes: in-order visible
                float x = s_tsel[mm*6+gtt*2+0];
                float y = s_tsel[mm*6+gtt*2+1];
                float4 c4 = *(const float4*)&s_csel[(mm*3+gtt)*4];
                SP += p; S1x += p*x; S1y += p*y;
                Sxx += p*x*x; Sxy += p*x*y; Syy += p*y*y;
                C0 += p*c4.x; C1 += p*c4.y; C2 += p*c4.z;
            }
            #define R8(v) { v += __shfl_down(v,4); v += __shfl_down(v,2); v += __shfl_down(v,1); }
            R8(SP) R8(S1x) R8(S1y) R8(Sxx) R8(Sxy) R8(Syy) R8(C0) R8(C1) R8(C2)
            #undef R8
            if (sub == 0) {
                float p6 = SP;
                float tx = __fdividef(S1x, p6), ty = __fdividef(S1y, p6);
                float rp = __fdividef(1.0f, p6);
                float c00 = (C0 + (Sxx - S1x*tx)) * rp;
                float c01 = (C1 + (Sxy - S1x*ty)) * rp;
                float c11 = (C2 + (Syy - S1y*ty)) * rp;
                float det = c00*c11 - c01*c01;
                float rdet = __fdividef(1.0f, det);
                s_prec[nxt][gid*3+0] =  c11*rdet;
                s_prec[nxt][gid*3+1] = -c01*rdet;
                s_prec[nxt][gid*3+2] =  c00*rdet;
                s_ld[nxt][gid] = __logf(det);
                s_t6sel[nxt][gn*6+gtt*2+0] = tx;
                s_t6sel[nxt][gn*6+gtt*2+1] = ty;
                if (gtt == 0) s_probas6[nxt][gn] = SP;
            }
        }
        WGSYNC();   // lgkm-only + s_barrier: DMA (vmcnt) stays in flight
    }

    // ========== full sync: DMA quarters + last E-step visible ==========
    WGSYNC_ALL();

    // ========== final full-T M-step, split 4 ways: 160 items=(t,half) ==========
    float*  out_p = g_out;
    float2* out_t = (float2*)(g_out + BATCH*NF);
    float4* out_c = (float4*)(g_out + BATCH*NF + BATCH*NF*T*2);
    if (lane < 40) {
        int it2 = wv*40 + lane;       // 0..159
        int t = it2 >> 1, half = it2 & 1;
        float SP[3]={0,0,0}, S1x[3]={0,0,0}, S1y[3]={0,0,0};
        float Sxx[3]={0,0,0}, Sxy[3]={0,0,0}, Syy[3]={0,0,0};
        float C00[3]={0,0,0}, C01[3]={0,0,0}, C11[3]={0,0,0};
        #pragma unroll 4
        for (int mm = 0; mm < M; ++mm) {
            float2 xy = ((const float2*)s_txy)[mm*T + t];
            float4 c4 = ((const float4*)s_cv4)[mm*T + t];
            float4 pq = *(const float4*)&s_Pm[mm*8 + half*4];
            float p[3] = {pq.x, pq.y, pq.z};
            float xx = xy.x*xy.x, xyv = xy.x*xy.y, yy = xy.y*xy.y;
            #pragma unroll
            for (int j = 0; j < 3; ++j) {
                SP[j]+=p[j]; S1x[j]+=p[j]*xy.x; S1y[j]+=p[j]*xy.y;
                Sxx[j]+=p[j]*xx; Sxy[j]+=p[j]*xyv; Syy[j]+=p[j]*yy;
                C00[j]+=p[j]*c4.x; C01[j]+=p[j]*c4.y; C11[j]+=p[j]*c4.w;
            }
        }
        #pragma unroll
        for (int j = 0; j < 3; ++j) {
            int n = half*3 + j;
            float p6 = SP[j];
            float tx = __fdividef(S1x[j], p6), ty = __fdividef(S1y[j], p6);
            float rp = __fdividef(1.0f, p6);
            float c00 = (C00[j] + (Sxx[j] - S1x[j]*tx)) * rp;
            float c01 = (C01[j] + (Sxy[j] - S1x[j]*ty)) * rp;
            float c11 = (C11[j] + (Syy[j] - S1y[j]*ty)) * rp;
            size_t o = (size_t)(b*NF + n)*T + t;
            out_t[o] = make_float2(tx, ty);
            out_c[o] = make_float4(c00, c01, c01, c11);
        }
    }
    if (wv == 0 && lane < NF) {
        int slot = (lane < 3) ? lane : lane + 1;
        float sp = 0.f;
        for (int mm = 0; mm < M; ++mm) sp += s_Pm[mm*8 + slot];
        out_p[b*NF + lane] = sp;
    }
}

extern "C" void kernel_launch(void* const* d_in, const int* in_sizes, int n_in,
                              void* d_out, int out_size, void* d_ws, size_t ws_size,
                              hipStream_t stream) {
    const float* logits = (const float*)d_in[0];
    const float* traj   = (const float*)d_in[1];
    const float* cov    = (const float*)d_in[2];
    float* out = (float*)d_out;
    em_kernel<<<dim3(BATCH), dim3(256), 0, stream>>>(logits, traj, cov, out);
}

// Round 7
// 105.429 us; speedup vs baseline: 1.2154x; 1.0715x over previous
//
#include <hip/hip_runtime.h>
#include <math.h>

#define BATCH 256
#define M 48
#define T 80
#define NF 6
#define EMIT 10
#define MM (M*M)        // 2304
#define KPW 9           // keys per lane per wave (2304 / 64 / 4)
#define LOG2PI 1.8378770664093453f

typedef unsigned int u32;
typedef unsigned long long u64;

// Raw workgroup sync: drains LDS (lgkm) only -- async global_load_lds DMA
// (vmcnt) stays in flight. "memory" clobber stops compiler caching LDS in regs.
#define WGSYNC()     __asm__ __volatile__("s_waitcnt lgkmcnt(0)\ns_barrier" ::: "memory")
#define WGSYNC_ALL() __asm__ __volatile__("s_waitcnt vmcnt(0) lgkmcnt(0)\ns_barrier" ::: "memory")

// 4 waves/block. Wave-parallel phases (E-step, greedy) run REDUNDANTLY on all
// waves (free). Work deeper than one wave's capacity (DMA, keys, radix
// histograms, stat346, adjacency, selector M-step, final M-step) is SPLIT
// across waves with cheap lgkm-only barriers. Per-wave-private histogram
// buffers per round remove all zeroing races (4 barriers for 4 radix rounds).
__global__ __launch_bounds__(256, 1)
void em_kernel(const float* __restrict__ g_logits,
               const float* __restrict__ g_traj,
               const float* __restrict__ g_cov,
               float* __restrict__ g_out)
{
    const int b = blockIdx.x;
    const int tid = threadIdx.x;
    const int lane = tid & 63;
    const int wv = tid >> 6;
    const int SEL[3] = {29, 49, 79};

    // ---- LDS ~122 KB ----
    __shared__ __align__(16) float s_txy[M*T*2];   // staged traj (DMA)
    __shared__ __align__(16) float s_cv4[M*T*4];   // staged cov (DMA)
    __shared__ float s_adj[MM];
    __shared__ float s_logits[M];
    __shared__ float s_probas[M];
    __shared__ float s_tsel[M*6];                  // [m][tt][d]
    __shared__ float s_d1[M*3];
    __shared__ __align__(16) float s_csel[M*3*4];  // [m][tt]{c00,c01,c11,pad}
    __shared__ __align__(16) float s_Pm[M*8];      // slots: 0-2=n0..2, 4-6=n3..5
    __shared__ float s_t6sel[2][NF*6];             // ping-pong EM state
    __shared__ float s_probas6[2][NF];
    __shared__ float s_prec[2][NF*3*3];
    __shared__ float s_ld[2][NF*3];
    __shared__ int   s_idx[8];
    __shared__ __align__(16) u32 s_hist[4][4][256]; // [wave][round] private hists
    __shared__ u32 s_statc[4], s_statm[4];

    const float* traj_b = g_traj + (size_t)b*(M*T*2);
    const float* cov_b  = g_cov  + (size_t)b*(M*T*4);

    // ========== direct gathers (redundant per wave) ==========
    float myLogit = -1e30f;
    if (lane < M) myLogit = g_logits[b*M + lane];
    float selx[3], sely[3], cc0[3], cc1[3], cc2[3];
    #pragma unroll
    for (int r = 0; r < 3; ++r) {
        int i = lane + r*64;
        if (i < M*3) {
            int m = i/3, tt = i - (i/3)*3;
            float2 xy = ((const float2*)traj_b)[m*T + SEL[tt]];
            float4 cv = ((const float4*)cov_b)[m*T + SEL[tt]];
            selx[r]=xy.x; sely[r]=xy.y; cc0[r]=cv.x; cc1[r]=cv.y; cc2[r]=cv.w;
        }
    }

    // ========== DMA staging, split 4 ways (per-wave vmcnt) ==========
    __builtin_amdgcn_sched_barrier(0);
    {
        const char* gt = (const char*)traj_b + lane*16;
        char* lt = (char*)s_txy;
        #pragma unroll 2
        for (int k = wv; k < 30; k += 4)
            __builtin_amdgcn_global_load_lds(
                (const __attribute__((address_space(1))) u32*)(gt + k*1024),
                (__attribute__((address_space(3))) u32*)(lt + k*1024), 16, 0, 0);
        const char* gc = (const char*)cov_b + lane*16;
        char* lc = (char*)s_cv4;
        #pragma unroll 2
        for (int k = wv; k < 60; k += 4)
            __builtin_amdgcn_global_load_lds(
                (const __attribute__((address_space(1))) u32*)(gc + k*1024),
                (__attribute__((address_space(3))) u32*)(lc + k*1024), 16, 0, 0);
    }
    __builtin_amdgcn_sched_barrier(0);

    // ========== zero own 4 hist buffers (program-order before own atomics) ====
    {
        uint4* hz = (uint4*)&s_hist[wv][0][0];     // 4*256 u32 = 256 uint4
        #pragma unroll
        for (int k = 0; k < 4; ++k) hz[lane + k*64] = make_uint4(0,0,0,0);
    }

    // ========== stage selector data (redundant identical writes) ==========
    if (lane < M) s_logits[lane] = myLogit;
    #pragma unroll
    for (int r = 0; r < 3; ++r) {
        int i = lane + r*64;
        if (i < M*3) {
            int m = i/3, tt = i - (i/3)*3;
            s_tsel[m*6+tt*2+0] = selx[r];
            s_tsel[m*6+tt*2+1] = sely[r];
            s_d1[i] = selx[r]*selx[r] + sely[r]*sely[r];
            s_csel[i*4+0]=cc0[r]; s_csel[i*4+1]=cc1[r]; s_csel[i*4+2]=cc2[r]; s_csel[i*4+3]=0.f;
        }
    }

    // ========== softmax (in-wave, registers) ==========
    float mx = myLogit;
    #pragma unroll
    for (int off = 32; off; off >>= 1) mx = fmaxf(mx, __shfl_xor(mx, off));
    float pe = (lane < M) ? __expf(myLogit - mx) : 0.f;
    float psum = pe;
    #pragma unroll
    for (int off = 32; off; off >>= 1) psum += __shfl_xor(psum, off);
    const float proba = pe / psum;
    if (lane < M) s_probas[lane] = proba;

    // ========== SQUARED distance keys (split: 9/lane) + round-1 histogram ====
    u32 key[KPW];
    {
        u32* h0 = &s_hist[wv][0][0];
        #pragma unroll
        for (int j = 0; j < KPW; ++j) {
            int e = lane + (wv*KPW + j)*64;
            int m = e/M, n = e - (e/M)*M;
            float dot = s_tsel[m*6+4]*s_tsel[n*6+4] + s_tsel[m*6+5]*s_tsel[n*6+5];
            float v = s_d1[m*3+2] + s_d1[n*3+2] - 2.0f*dot;
            key[j] = __float_as_uint(fmaxf(v, 0.0f));  // nonneg: uint order == float order
            atomicAdd(&h0[key[j] >> 24], 1u);
        }
    }

    // ========== exact order stat 345: 4-round radix over split keys ==========
    int target = 345;
    u32 prefix = 0u, pmask = 0u;
    #pragma unroll 1
    for (int r = 0; r < 4; ++r) {
        const int shift = 24 - 8*r;
        if (r) {
            u32* hr = &s_hist[wv][r][0];
            #pragma unroll
            for (int j = 0; j < KPW; ++j) {
                if ((key[j] & pmask) == prefix)
                    atomicAdd(&hr[(key[j] >> shift) & 255u], 1u);
            }
        }
        WGSYNC();   // own atomics drained; partners' partials visible
        uint4 h0 = ((const uint4*)&s_hist[0][r][0])[lane];
        uint4 h1 = ((const uint4*)&s_hist[1][r][0])[lane];
        uint4 h2 = ((const uint4*)&s_hist[2][r][0])[lane];
        uint4 h3 = ((const uint4*)&s_hist[3][r][0])[lane];
        uint4 hv = make_uint4(h0.x+h1.x+h2.x+h3.x, h0.y+h1.y+h2.y+h3.y,
                              h0.z+h1.z+h2.z+h3.z, h0.w+h1.w+h2.w+h3.w);
        u32 s4 = hv.x + hv.y + hv.z + hv.w;
        u32 cum = s4;
        #pragma unroll
        for (int off = 1; off < 64; off <<= 1) {
            u32 u = __shfl_up(cum, off);
            if (lane >= off) cum += u;
        }
        u64 bmask = __ballot(cum > (u32)target);
        int g = __builtin_ctzll(bmask);
        int dig = 0; u32 binstart = 0;
        if (lane == g) {
            u32 exc = cum - s4;
            int bi2 = lane*4;
            if (exc + hv.x > (u32)target)      { dig = bi2;   binstart = exc; }
            else { exc += hv.x;
                if (exc + hv.y > (u32)target)  { dig = bi2+1; binstart = exc; }
                else { exc += hv.y;
                    if (exc + hv.z > (u32)target) { dig = bi2+2; binstart = exc; }
                    else { exc += hv.z;            dig = bi2+3; binstart = exc; } } }
        }
        dig = __shfl(dig, g);
        binstart = (u32)__shfl((int)binstart, g);
        target -= (int)binstart;
        prefix |= ((u32)dig) << shift;
        pmask  |= (255u << shift);
    }
    const u32 k1 = prefix;                 // squared order stat 345
    const float v1f = sqrtf(__uint_as_float(k1));

    // ========== order stat 346: split partials + 1-barrier combine ==========
    {
        u32 cnt = 0, mng = 0xFFFFFFFFu;
        #pragma unroll
        for (int j = 0; j < KPW; ++j) {
            if (key[j] <= k1) cnt++;
            else mng = (key[j] < mng) ? key[j] : mng;
        }
        #pragma unroll
        for (int off = 32; off > 0; off >>= 1) {
            cnt += __shfl_down(cnt, off);
            u32 mo = (u32)__shfl_down((int)mng, off);
            mng = (mo < mng) ? mo : mng;
        }
        if (lane == 0) { s_statc[wv] = cnt; s_statm[wv] = mng; }
    }
    WGSYNC();
    float v2f;
    {
        u32 ct = s_statc[0]+s_statc[1]+s_statc[2]+s_statc[3];
        u32 mt = s_statm[0];
        if (s_statm[1] < mt) mt = s_statm[1];
        if (s_statm[2] < mt) mt = s_statm[2];
        if (s_statm[3] < mt) mt = s_statm[3];
        v2f = (ct >= 347u) ? v1f : sqrtf(__uint_as_float(mt));
    }
    const float qi = 0.15f * 2303.0f;
    const float fr = qi - floorf(qi);
    const float thr = v1f*(1.0f - fr) + v2f*fr;

    // exact squared threshold: dthr = max{u : fl(sqrt(u)) <= thr}
    float dthr;
    {
        u32 ub = __float_as_uint(thr*thr);
        while (sqrtf(__uint_as_float(ub)) > thr) --ub;        // <=2 iters
        while (sqrtf(__uint_as_float(ub+1u)) <= thr) ++ub;    // <=2 iters
        dthr = __uint_as_float(ub);
    }

    // ========== adjacency, squared-space (split: 9/lane) ==========
    #pragma unroll
    for (int j = 0; j < KPW; ++j) {
        int e = lane + (wv*KPW + j)*64;
        int m = e/M, n = e - (e/M)*M;
        float d0 = s_tsel[m*6+0]*s_tsel[n*6+0] + s_tsel[m*6+1]*s_tsel[n*6+1];
        float v0 = fmaxf(s_d1[m*3+0] + s_d1[n*3+0] - 2.0f*d0, 0.0f);
        float d1v = s_tsel[m*6+2]*s_tsel[n*6+2] + s_tsel[m*6+3]*s_tsel[n*6+3];
        float v1 = fmaxf(s_d1[m*3+1] + s_d1[n*3+1] - 2.0f*d1v, 0.0f);
        bool a = (__uint_as_float(key[j]) <= dthr) && (v0 <= dthr) && (v1 <= dthr);
        s_adj[e] = a ? 1.0f : 0.0f;
    }
    WGSYNC();

    // ========== greedy selection (redundant per wave) ==========
    const int m = (lane < M) ? lane : (M-1);
    {
        float base = 0.f;
        #pragma unroll
        for (int n = 0; n < M; ++n) base += s_adj[n*M+m] * s_probas[n];
        float worked = 1.f;
        #pragma unroll 1
        for (int k = 0; k < NF; ++k) {
            float sc = (lane < M) ? base*worked : -1.f;
            int bi = lane;
            #pragma unroll
            for (int off = 32; off; off >>= 1) {
                float so = __shfl_down(sc, off);
                int io = __shfl_down(bi, off);
                if (so > sc || (so == sc && io < bi)) { sc = so; bi = io; }
            }
            int amax = __shfl(bi, 0);   // first-max == jnp.argmax
            if (lane == 0) s_idx[k] = amax;
            worked *= (1.f - s_adj[amax*M+m]);
        }
    }

    // ========== EM init -> buffer 0 (redundant identical writes) ==========
    if (lane < NF) {
        float mx6 = -1e30f;
        #pragma unroll
        for (int j = 0; j < NF; ++j) mx6 = fmaxf(mx6, s_logits[s_idx[j]]);
        float sum6 = 0.f;
        #pragma unroll
        for (int j = 0; j < NF; ++j) sum6 += __expf(s_logits[s_idx[j]] - mx6);
        s_probas6[0][lane] = __expf(s_logits[s_idx[lane]] - mx6) / sum6;
    }
    if (lane < NF*3) {
        int n = lane/3, tt = lane - (lane/3)*3;
        int m0 = s_idx[n];
        s_t6sel[0][n*6+tt*2+0] = s_tsel[m0*6+tt*2+0];
        s_t6sel[0][n*6+tt*2+1] = s_tsel[m0*6+tt*2+1];
        float c00 = s_csel[(m0*3+tt)*4+0];
        float c01 = s_csel[(m0*3+tt)*4+1];
        float c11 = s_csel[(m0*3+tt)*4+2];
        float det = c00*c11 - c01*c01;
        float rdet = __fdividef(1.0f, det);
        s_prec[0][lane*3+0] =  c11*rdet;
        s_prec[0][lane*3+1] = -c01*rdet;
        s_prec[0][lane*3+2] =  c00*rdet;
        s_ld[0][lane] = __logf(det);
    }

    // ========== EM loop: redundant E-step + SPLIT selector M-step ==========
    float tm0=s_tsel[m*6+0], tm1=s_tsel[m*6+1], tm2=s_tsel[m*6+2],
          tm3=s_tsel[m*6+3], tm4=s_tsel[m*6+4], tm5=s_tsel[m*6+5];
    const int gid = tid >> 3;          // 8-lane group id, 0..31 (18 active)
    const int sub = tid & 7;
    const int gn  = gid/3, gtt = gid - (gid/3)*3;      // valid when gid<18
    const int gslot = (gn < 3) ? gn : gn + 1;

    #pragma unroll 1
    for (int it = 0; it < EMIT; ++it) {
        const int cur = it & 1, nxt = cur ^ 1;
        const float* prC = s_prec[cur];
        const float* ldC = s_ld[cur];
        const float* t6C = s_t6sel[cur];
        const float* p6C = s_probas6[cur];

        // ---- E-step (all waves, lane = m): broadcast LDS reads ----
        float num[NF]; float den = 1e-8f;
        #pragma unroll
        for (int n = 0; n < NF; ++n) {
            float lsum = ldC[n*3+0] + ldC[n*3+1] + ldC[n*3+2];
            float dx0 = t6C[n*6+0]-tm0, dy0 = t6C[n*6+1]-tm1;
            float dx1 = t6C[n*6+2]-tm2, dy1 = t6C[n*6+3]-tm3;
            float dx2 = t6C[n*6+4]-tm4, dy2 = t6C[n*6+5]-tm5;
            float q = prC[(n*3+0)*3+0]*dx0*dx0 + 2.f*prC[(n*3+0)*3+1]*dx0*dy0 + prC[(n*3+0)*3+2]*dy0*dy0
                    + prC[(n*3+1)*3+0]*dx1*dx1 + 2.f*prC[(n*3+1)*3+1]*dx1*dy1 + prC[(n*3+1)*3+2]*dy1*dy1
                    + prC[(n*3+2)*3+0]*dx2*dx2 + 2.f*prC[(n*3+2)*3+1]*dx2*dy2 + prC[(n*3+2)*3+2]*dy2*dy2;
            num[n] = (__expf(-3.f*LOG2PI - 0.5f*lsum - 0.5f*q) + 1e-8f) * p6C[n];
            den += num[n];
        }
        float f = __fdividef(proba, den);
        if (lane < M) {   // identical-value writes from all 4 waves: race-safe
            *(float4*)&s_Pm[m*8]   = make_float4(num[0]*f, num[1]*f, num[2]*f, 0.f);
            *(float4*)&s_Pm[m*8+4] = make_float4(num[3]*f, num[4]*f, num[5]*f, 0.f);
        }
        if (it == EMIT-1) break;

        // ---- selector M-step SPLIT: 18 items x 8-lane groups, 6-deep loops ----
        if (gid < 18) {
            float SP=0,S1x=0,S1y=0,Sxx=0,Sxy=0,Syy=0,C0=0,C1=0,C2=0;
            #pragma unroll
            for (int k = 0; k < 6; ++k) {
                int mm = sub*6 + k;
                float p = s_Pm[mm*8 + gslot];     // own-wave writes: in-order visible
                float x = s_tsel[mm*6+gtt*2+0];
                float y = s_tsel[mm*6+gtt*2+1];
                float4 c4 = *(const float4*)&s_csel[(mm*3+gtt)*4];
                SP += p; S1x += p*x; S1y += p*y;
                Sxx += p*x*x; Sxy += p*x*y; Syy += p*y*y;
                C0 += p*c4.x; C1 += p*c4.y; C2 += p*c4.z;
            }
            #define R8(v) { v += __shfl_down(v,4); v += __shfl_down(v,2); v += __shfl_down(v,1); }
            R8(SP) R8(S1x) R8(S1y) R8(Sxx) R8(Sxy) R8(Syy) R8(C0) R8(C1) R8(C2)
            #undef R8
            if (sub == 0) {
                float p6 = SP;
                float tx = __fdividef(S1x, p6), ty = __fdividef(S1y, p6);
                float rp = __fdividef(1.0f, p6);
                float c00 = (C0 + (Sxx - S1x*tx)) * rp;
                float c01 = (C1 + (Sxy - S1x*ty)) * rp;
                float c11 = (C2 + (Syy - S1y*ty)) * rp;
                float det = c00*c11 - c01*c01;
                float rdet = __fdividef(1.0f, det);
                s_prec[nxt][gid*3+0] =  c11*rdet;
                s_prec[nxt][gid*3+1] = -c01*rdet;
                s_prec[nxt][gid*3+2] =  c00*rdet;
                s_ld[nxt][gid] = __logf(det);
                s_t6sel[nxt][gn*6+gtt*2+0] = tx;
                s_t6sel[nxt][gn*6+gtt*2+1] = ty;
                if (gtt == 0) s_probas6[nxt][gn] = SP;
            }
        }
        WGSYNC();   // lgkm-only + s_barrier: DMA (vmcnt) stays in flight
    }

    // ========== full sync: DMA quarters + last E-step visible ==========
    WGSYNC_ALL();

    // ========== final full-T M-step: 240 items=(t,third), 60 lanes/wave =======
    float*  out_p = g_out;
    float2* out_t = (float2*)(g_out + BATCH*NF);
    float4* out_c = (float4*)(g_out + BATCH*NF + BATCH*NF*T*2);
    if (lane < 60) {
        int idx = wv*60 + lane;       // 0..239
        int t = idx/3, third = idx - (idx/3)*3;
        int nA = third*2, nB = nA + 1;
        int slotA = (nA < 3) ? nA : nA + 1;
        int slotB = (nB < 3) ? nB : nB + 1;
        float SPa=0,S1xa=0,S1ya=0,Sxxa=0,Sxya=0,Syya=0,C00a=0,C01a=0,C11a=0;
        float SPb=0,S1xb=0,S1yb=0,Sxxb=0,Sxyb=0,Syyb=0,C00b=0,C01b=0,C11b=0;
        #pragma unroll 4
        for (int mm = 0; mm < M; ++mm) {
            float2 xy = ((const float2*)s_txy)[mm*T + t];
            float4 c4 = ((const float4*)s_cv4)[mm*T + t];
            float pa = s_Pm[mm*8 + slotA];
            float pb = s_Pm[mm*8 + slotB];
            float xx = xy.x*xy.x, xyv = xy.x*xy.y, yy = xy.y*xy.y;
            SPa+=pa; S1xa+=pa*xy.x; S1ya+=pa*xy.y;
            Sxxa+=pa*xx; Sxya+=pa*xyv; Syya+=pa*yy;
            C00a+=pa*c4.x; C01a+=pa*c4.y; C11a+=pa*c4.w;
            SPb+=pb; S1xb+=pb*xy.x; S1yb+=pb*xy.y;
            Sxxb+=pb*xx; Sxyb+=pb*xyv; Syyb+=pb*yy;
            C00b+=pb*c4.x; C01b+=pb*c4.y; C11b+=pb*c4.w;
        }
        {
            float p6 = SPa;
            float tx = __fdividef(S1xa, p6), ty = __fdividef(S1ya, p6);
            float rp = __fdividef(1.0f, p6);
            float c00 = (C00a + (Sxxa - S1xa*tx)) * rp;
            float c01 = (C01a + (Sxya - S1xa*ty)) * rp;
            float c11 = (C11a + (Syya - S1ya*ty)) * rp;
            size_t o = (size_t)(b*NF + nA)*T + t;
            out_t[o] = make_float2(tx, ty);
            out_c[o] = make_float4(c00, c01, c01, c11);
        }
        {
            float p6 = SPb;
            float tx = __fdividef(S1xb, p6), ty = __fdividef(S1yb, p6);
            float rp = __fdividef(1.0f, p6);
            float c00 = (C00b + (Sxxb - S1xb*tx)) * rp;
            float c01 = (C01b + (Sxyb - S1xb*ty)) * rp;
            float c11 = (C11b + (Syyb - S1yb*ty)) * rp;
            size_t o = (size_t)(b*NF + nB)*T + t;
            out_t[o] = make_float2(tx, ty);
            out_c[o] = make_float4(c00, c01, c01, c11);
        }
    }
    if (wv == 0 && lane < NF) {
        int slot = (lane < 3) ? lane : lane + 1;
        float sp = 0.f;
        for (int mm = 0; mm < M; ++mm) sp += s_Pm[mm*8 + slot];
        out_p[b*NF + lane] = sp;
    }
}

extern "C" void kernel_launch(void* const* d_in, const int* in_sizes, int n_in,
                              void* d_out, int out_size, void* d_ws, size_t ws_size,
                              hipStream_t stream) {
    const float* logits = (const float*)d_in[0];
    const float* traj   = (const float*)d_in[1];
    const float* cov    = (const float*)d_in[2];
    float* out = (float*)d_out;
    em_kernel<<<dim3(BATCH), dim3(256), 0, stream>>>(logits, traj, cov, out);
}